// Round 9
// baseline (318.424 us; speedup 1.0000x reference)
//
#include <hip/hip_runtime.h>
#include <hip/hip_fp16.h>
#include <cstdint>
#include <cstddef>

// z = soft_thresh(Toeplitz(v) @ x + W2 @ y, beta) -- complex, N=1024, M=256, B=1024
// Real embedding: C[1024][2048] = A'[1024][2560] @ B'[2560][2048] (layouts R0-R5).
// Output = Re(z) only: [1024,1024] f32 (R4 finding).
//
// R9 (R8: partial traffic + dispatch count dominate; harness fill ~48us is fixed):
//  - 2 dispatches: build_all, gemm_fused
//  - split-K=2 (K=1280), 1024 blocks (4/CU, 16 waves/CU), dbuf LDS, 1 barrier/iter
//  - reduce fused into gemm: last-arriver per tile (threadfence + atomic counter)
//    reads other split's 16KB partial, soft-thresholds, writes Re out
//  - bid pairing (b, b+8) puts both splits of a tile on one XCD (perf heuristic
//    only; correctness from device-scope fences)

#define K_DIM 2560
#define BETA_F 0.01f
#define EPS_F  1e-12f

typedef __attribute__((ext_vector_type(8))) _Float16 half8;
typedef __attribute__((ext_vector_type(4))) _Float16 half4;
typedef __attribute__((ext_vector_type(4))) float   floatx4;

__device__ alignas(16) _Float16 g_Ap[1024 * K_DIM];      // 5 MB
__device__ alignas(16) _Float16 g_Bt[2048 * K_DIM];      // 10 MB
__device__ alignas(16) float    g_P[2][1024 * 2048];     // 16 MB split partials
__device__ int g_cnt[512];                               // per-tile arrival count

// ---------------- prep (merged): build A', B', zero counters -----------------
__global__ __launch_bounds__(256) void build_all(
    const float* __restrict__ v_re, const float* __restrict__ v_im,
    const float* __restrict__ W2_re, const float* __restrict__ W2_im,
    const float* __restrict__ x_re, const float* __restrict__ x_im,
    const float* __restrict__ y_re, const float* __restrict__ y_im)
{
    const int bx = blockIdx.x;
    if (bx < 1280) {
        // ---- A' part: one thread per 8 halves (16B store) ----
        int t = bx * 256 + threadIdx.x;
        if (t < 512) g_cnt[t] = 0;             // reset tile counters every call
        int i  = t / 320;
        int c  = t - i * 320;
        int kp = c * 8;                        // segment-aligned
        half8 h;
        if (kp < 1024) {
#pragma unroll
            for (int j = 0; j < 8; ++j) h[j] = (_Float16)v_re[1023 + i - kp - j];
        } else if (kp < 1280) {
            const float* s = W2_re + i * 256 + (kp - 1024);
#pragma unroll
            for (int j = 0; j < 8; ++j) h[j] = (_Float16)s[j];
        } else if (kp < 2304) {
            int k2 = kp - 1280;
#pragma unroll
            for (int j = 0; j < 8; ++j) h[j] = (_Float16)v_im[1023 + i - k2 - j];
        } else {
            const float* s = W2_im + i * 256 + (kp - 2304);
#pragma unroll
            for (int j = 0; j < 8; ++j) h[j] = (_Float16)s[j];
        }
        *reinterpret_cast<half8*>(g_Ap + (size_t)i * K_DIM + kp) = h;
        return;
    }
    // ---- B' part: transposing build ----
    __shared__ float lre[32][33];
    __shared__ float lim[32][33];
    int idx = bx - 1280;                       // 0..1279
    int bk  = idx % 40;                        // 0..39 (k-block / source select)
    int by  = idx / 40;                        // 0..31 (n-block)
    const float* sre = (bk < 32) ? x_re : y_re;
    const float* sim = (bk < 32) ? x_im : y_im;
    int kb   = (bk < 32) ? bk : (bk - 32);
    int koff = (bk < 32) ? 0 : 1024;
    int k0 = kb * 32;
    int n0 = by * 32;
    int tid = threadIdx.x;
    int tx = tid & 31, ty = tid >> 5;
#pragma unroll
    for (int s = 0; s < 4; ++s) {
        int kk = ty + 8 * s;
        lre[kk][tx] = sre[(size_t)(k0 + kk) * 1024 + n0 + tx];
        lim[kk][tx] = sim[(size_t)(k0 + kk) * 1024 + n0 + tx];
    }
    __syncthreads();
    int lane_n = tid >> 3;                     // 0..31
    int kq     = (tid & 7) * 4;                // 0,4,...,28
    half4 hre, him, hmim;
#pragma unroll
    for (int j = 0; j < 4; ++j) {
        float re = lre[kq + j][lane_n];
        float im = lim[kq + j][lane_n];
        hre[j]  = (_Float16)re;
        him[j]  = (_Float16)im;
        hmim[j] = (_Float16)(-im);
    }
    int n = n0 + lane_n;
    size_t kk2 = (size_t)koff + k0 + kq;
    _Float16* r0 = g_Bt + (size_t)(2 * n)     * K_DIM;
    _Float16* r1 = g_Bt + (size_t)(2 * n + 1) * K_DIM;
    *reinterpret_cast<half4*>(r0 + kk2)        = hre;   // Br block of re-col
    *reinterpret_cast<half4*>(r0 + kk2 + 1280) = hmim;  // -Bi block of re-col
    *reinterpret_cast<half4*>(r1 + kk2)        = him;   // Bi block of im-col
    *reinterpret_cast<half4*>(r1 + kk2 + 1280) = hre;   // Br block of im-col
}

// ---------------- split-K=2 GEMM + fused last-arriver reduce/soft-thresh ----
// 64x64 tile, BK=64, 1024 blocks (4/CU), 4 waves = 2x2 of 32x32.
// Dbuf LDS, one barrier/iter, XOR swizzle (0 conflicts R5-R8).
__global__ __launch_bounds__(256, 4) void gemm_fused(float* __restrict__ out,
                                                     int out_n)
{
    __shared__ __align__(16) _Float16 As[2 * 2 * 64 * 32];  // [buf][ksub][row][32h]
    __shared__ __align__(16) _Float16 Bs[2 * 2 * 64 * 32];
    __shared__ int sLast;

    const int tid  = threadIdx.x;
    const int lane = tid & 63;
    const int w    = tid >> 6;
    const int wm   = w >> 1;
    const int wn   = w & 1;

    // bids b and b^8 share XCD (round-robin heuristic) and tile, differ in split
    const int bid    = blockIdx.x;       // 0..1023
    const int split  = (bid >> 3) & 1;
    const int tileId = (bid & 7) | ((bid >> 4) << 3);     // 0..511
    const int xcd    = tileId & 7;
    const int t      = tileId >> 3;      // 0..63 in XCD's 8x8 super-tile
    const int mi0 = ((xcd & 1) * 8 + (t & 7)) * 64;       // 0..960
    const int ni0 = ((xcd >> 1) * 8 + (t >> 3)) * 64;     // 0..1984
    const int ks  = split * 1280;
    float* __restrict__ P = g_P[split];

    floatx4 acc[2][2];
#pragma unroll
    for (int a = 0; a < 2; ++a)
#pragma unroll
        for (int b = 0; b < 2; ++b) acc[a][b] = (floatx4)0.0f;

    const int rS = tid >> 2;
    const int jS = tid & 3;
    const int s0 = ((rS & 15) >> 1) & 3;
    char* asW = (char*)As + rS * 64 + ((jS ^ s0) * 16);
    char* bsW = (char*)Bs + rS * 64 + ((jS ^ s0) * 16);
    const _Float16* gA = g_Ap + (size_t)(mi0 + rS) * K_DIM + ks + jS * 8;
    const _Float16* gB = g_Bt + (size_t)(ni0 + rS) * K_DIM + ks + jS * 8;

    const int rowA = lane & 15;
    const int q    = lane >> 4;
    const int coff = (q ^ ((rowA >> 1) & 3)) * 16;

    {   // preload iter 0 -> buf 0
        half8 pA0 = *reinterpret_cast<const half8*>(gA);
        half8 pA1 = *reinterpret_cast<const half8*>(gA + 32);
        half8 pB0 = *reinterpret_cast<const half8*>(gB);
        half8 pB1 = *reinterpret_cast<const half8*>(gB + 32);
        *reinterpret_cast<half8*>(asW)        = pA0;
        *reinterpret_cast<half8*>(asW + 4096) = pA1;
        *reinterpret_cast<half8*>(bsW)        = pB0;
        *reinterpret_cast<half8*>(bsW + 4096) = pB1;
    }
    __syncthreads();

    const int NIT = 1280 / 64;           // 20
    for (int kt = 0; kt < NIT; ++kt) {
        const int cur = kt & 1;
        half8 pA0, pA1, pB0, pB1;
        if (kt < NIT - 1) {              // issue next slab's global loads now
            const _Float16* ga = gA + (kt + 1) * 64;
            const _Float16* gb = gB + (kt + 1) * 64;
            pA0 = *reinterpret_cast<const half8*>(ga);
            pA1 = *reinterpret_cast<const half8*>(ga + 32);
            pB0 = *reinterpret_cast<const half8*>(gb);
            pB1 = *reinterpret_cast<const half8*>(gb + 32);
        }
        const char* Ab = (const char*)As + cur * 8192;
        const char* Bb = (const char*)Bs + cur * 8192;
        half8 af[2][2], bf[2][2];
#pragma unroll
        for (int mi = 0; mi < 2; ++mi) {
            int r = wm * 32 + mi * 16 + rowA;
            af[mi][0] = *reinterpret_cast<const half8*>(Ab + r * 64 + coff);
            af[mi][1] = *reinterpret_cast<const half8*>(Ab + 4096 + r * 64 + coff);
        }
#pragma unroll
        for (int ni = 0; ni < 2; ++ni) {
            int r = wn * 32 + ni * 16 + rowA;
            bf[ni][0] = *reinterpret_cast<const half8*>(Bb + r * 64 + coff);
            bf[ni][1] = *reinterpret_cast<const half8*>(Bb + 4096 + r * 64 + coff);
        }
#pragma unroll
        for (int mi = 0; mi < 2; ++mi)
#pragma unroll
            for (int ni = 0; ni < 2; ++ni) {
                acc[mi][ni] = __builtin_amdgcn_mfma_f32_16x16x32_f16(
                    af[mi][0], bf[ni][0], acc[mi][ni], 0, 0, 0);
                acc[mi][ni] = __builtin_amdgcn_mfma_f32_16x16x32_f16(
                    af[mi][1], bf[ni][1], acc[mi][ni], 0, 0, 0);
            }
        if (kt < NIT - 1) {              // store prefetch into the other buffer
            char* aw = asW + (cur ^ 1) * 8192;
            char* bw = bsW + (cur ^ 1) * 8192;
            *reinterpret_cast<half8*>(aw)        = pA0;
            *reinterpret_cast<half8*>(aw + 4096) = pA1;
            *reinterpret_cast<half8*>(bw)        = pB0;
            *reinterpret_cast<half8*>(bw + 4096) = pB1;
        }
        __syncthreads();                 // single barrier per iter
    }

    // ---- publish partial (C/D layout: col=lane&15, row=(lane>>4)*4+reg) ----
    const int colL  = lane & 15;
    const int rquad = (lane >> 4) * 4;
#pragma unroll
    for (int mi = 0; mi < 2; ++mi)
#pragma unroll
        for (int ni = 0; ni < 2; ++ni)
#pragma unroll
            for (int r = 0; r < 4; ++r) {
                int row = mi0 + wm * 32 + mi * 16 + rquad + r;
                int col = ni0 + wn * 32 + ni * 16 + colL;
                P[(size_t)row * 2048 + col] = acc[mi][ni][r];
            }
    __threadfence();                     // release: partial visible device-wide
    __syncthreads();                     // all threads' stores fenced
    if (tid == 0)
        sLast = (atomicAdd(&g_cnt[tileId], 1) == 1);
    __syncthreads();
    if (!sLast) return;                  // first arriver done

    // ---- last arriver: add other split's partial, soft-thresh, write Re ----
    __threadfence();                     // acquire
    const float* __restrict__ O = g_P[split ^ 1];
#pragma unroll
    for (int mi = 0; mi < 2; ++mi)
#pragma unroll
        for (int ni = 0; ni < 2; ++ni)
#pragma unroll
            for (int r = 0; r < 4; ++r) {
                int row = mi0 + wm * 32 + mi * 16 + rquad + r;
                int col = ni0 + wn * 32 + ni * 16 + colL;
                float c = acc[mi][ni][r] + O[(size_t)row * 2048 + col];
                float p = __shfl_xor(c, 1, 64);
                float mag = sqrtf(c * c + p * p);
                float s = fmaxf(mag - BETA_F, 0.0f) / fmaxf(mag, EPS_F);
                if ((col & 1) == 0) {                    // even = Re lane
                    size_t idx = (size_t)row * 1024 + (col >> 1);
                    if (idx < (size_t)out_n) out[idx] = c * s;
                }
            }
}

// ---------------- launcher ---------------------------------------------------
extern "C" void kernel_launch(void* const* d_in, const int* in_sizes, int n_in,
                              void* d_out, int out_size, void* d_ws, size_t ws_size,
                              hipStream_t stream) {
    (void)d_ws; (void)ws_size; (void)in_sizes; (void)n_in;
    const float* v_re  = (const float*)d_in[0];
    const float* v_im  = (const float*)d_in[1];
    const float* W2_re = (const float*)d_in[2];
    const float* W2_im = (const float*)d_in[3];
    const float* x_re  = (const float*)d_in[4];
    const float* x_im  = (const float*)d_in[5];
    const float* y_re  = (const float*)d_in[6];
    const float* y_im  = (const float*)d_in[7];
    float* out = (float*)d_out;

    build_all<<<2560, 256, 0, stream>>>(v_re, v_im, W2_re, W2_im,
                                        x_re, x_im, y_re, y_im);
    gemm_fused<<<1024, 256, 0, stream>>>(out, out_size);
}

// Round 10
// 115.246 us; speedup vs baseline: 2.7630x; 2.7630x over previous
//
#include <hip/hip_runtime.h>
#include <hip/hip_fp16.h>
#include <cstdint>
#include <cstddef>

// z = soft_thresh(Toeplitz(v) @ x + W2 @ y, beta) -- complex, N=1024, M=256, B=1024
// Real embedding: C[1024][2048] = A'[1024][2560] @ B'[2560][2048] (layouts R0-R5).
// Output = Re(z) only: [1024,1024] f32 (R4 finding).
//
// R10 (R9 lesson: device-scope fences per block serialize cross-XCD L2 -> 254us;
// reduction goes back to its own dispatch. R7 = best total 116.9):
//  - 3 dispatches: build_all, gemm_split (split-K=2), reduce_soft
//  - gemm: 2-DEEP register prefetch (slab k+2 issued a full iter before its LDS
//    store) to pull ~500cyc load latency out of the 20-iter serial chain
//  - dbuf LDS, one barrier/iter, XOR swizzle (0 conflicts R5-R9)

#define K_DIM 2560
#define BETA_F 0.01f
#define EPS_F  1e-12f

typedef __attribute__((ext_vector_type(8))) _Float16 half8;
typedef __attribute__((ext_vector_type(4))) _Float16 half4;
typedef __attribute__((ext_vector_type(4))) float   floatx4;

__device__ alignas(16) _Float16 g_Ap[1024 * K_DIM];      // 5 MB
__device__ alignas(16) _Float16 g_Bt[2048 * K_DIM];      // 10 MB
__device__ alignas(16) float    g_P[2][1024 * 2048];     // 16 MB split partials

// ---------------- prep (merged): build A' and B' -----------------------------
__global__ __launch_bounds__(256) void build_all(
    const float* __restrict__ v_re, const float* __restrict__ v_im,
    const float* __restrict__ W2_re, const float* __restrict__ W2_im,
    const float* __restrict__ x_re, const float* __restrict__ x_im,
    const float* __restrict__ y_re, const float* __restrict__ y_im)
{
    const int bx = blockIdx.x;
    if (bx < 1280) {
        // ---- A' part: one thread per 8 halves (16B store) ----
        int t = bx * 256 + threadIdx.x;
        int i  = t / 320;
        int c  = t - i * 320;
        int kp = c * 8;                        // segment-aligned
        half8 h;
        if (kp < 1024) {
#pragma unroll
            for (int j = 0; j < 8; ++j) h[j] = (_Float16)v_re[1023 + i - kp - j];
        } else if (kp < 1280) {
            const float* s = W2_re + i * 256 + (kp - 1024);
#pragma unroll
            for (int j = 0; j < 8; ++j) h[j] = (_Float16)s[j];
        } else if (kp < 2304) {
            int k2 = kp - 1280;
#pragma unroll
            for (int j = 0; j < 8; ++j) h[j] = (_Float16)v_im[1023 + i - k2 - j];
        } else {
            const float* s = W2_im + i * 256 + (kp - 2304);
#pragma unroll
            for (int j = 0; j < 8; ++j) h[j] = (_Float16)s[j];
        }
        *reinterpret_cast<half8*>(g_Ap + (size_t)i * K_DIM + kp) = h;
        return;
    }
    // ---- B' part: transposing build ----
    __shared__ float lre[32][33];
    __shared__ float lim[32][33];
    int idx = bx - 1280;                       // 0..1279
    int bk  = idx % 40;                        // 0..39 (k-block / source select)
    int by  = idx / 40;                        // 0..31 (n-block)
    const float* sre = (bk < 32) ? x_re : y_re;
    const float* sim = (bk < 32) ? x_im : y_im;
    int kb   = (bk < 32) ? bk : (bk - 32);
    int koff = (bk < 32) ? 0 : 1024;
    int k0 = kb * 32;
    int n0 = by * 32;
    int tid = threadIdx.x;
    int tx = tid & 31, ty = tid >> 5;
#pragma unroll
    for (int s = 0; s < 4; ++s) {
        int kk = ty + 8 * s;
        lre[kk][tx] = sre[(size_t)(k0 + kk) * 1024 + n0 + tx];
        lim[kk][tx] = sim[(size_t)(k0 + kk) * 1024 + n0 + tx];
    }
    __syncthreads();
    int lane_n = tid >> 3;                     // 0..31
    int kq     = (tid & 7) * 4;                // 0,4,...,28
    half4 hre, him, hmim;
#pragma unroll
    for (int j = 0; j < 4; ++j) {
        float re = lre[kq + j][lane_n];
        float im = lim[kq + j][lane_n];
        hre[j]  = (_Float16)re;
        him[j]  = (_Float16)im;
        hmim[j] = (_Float16)(-im);
    }
    int n = n0 + lane_n;
    size_t kk2 = (size_t)koff + k0 + kq;
    _Float16* r0 = g_Bt + (size_t)(2 * n)     * K_DIM;
    _Float16* r1 = g_Bt + (size_t)(2 * n + 1) * K_DIM;
    *reinterpret_cast<half4*>(r0 + kk2)        = hre;   // Br block of re-col
    *reinterpret_cast<half4*>(r0 + kk2 + 1280) = hmim;  // -Bi block of re-col
    *reinterpret_cast<half4*>(r1 + kk2)        = him;   // Bi block of im-col
    *reinterpret_cast<half4*>(r1 + kk2 + 1280) = hre;   // Br block of im-col
}

// ---------------- split-K=2 GEMM (partials only), 2-deep prefetch ------------
// 64x64 tile, BK=64, 1024 blocks (4/CU, 16 waves/CU), 4 waves = 2x2 of 32x32.
__global__ __launch_bounds__(256, 4) void gemm_split(void)
{
    __shared__ __align__(16) _Float16 As[2 * 2 * 64 * 32];  // [buf][ksub][row][32h]
    __shared__ __align__(16) _Float16 Bs[2 * 2 * 64 * 32];

    const int tid  = threadIdx.x;
    const int lane = tid & 63;
    const int w    = tid >> 6;
    const int wm   = w >> 1;
    const int wn   = w & 1;

    const int bid   = blockIdx.x;        // 0..1023
    const int split = bid >> 9;          // 0/1 -> k-offset 0/1280 (R7 mapping)
    const int sb    = bid & 511;
    const int xcd   = sb & 7;
    const int t     = sb >> 3;           // 0..63 in XCD's 8x8 super-tile
    const int mi0 = ((xcd & 1) * 8 + (t & 7)) * 64;       // 0..960
    const int ni0 = ((xcd >> 1) * 8 + (t >> 3)) * 64;     // 0..1984
    const int ks  = split * 1280;
    float* __restrict__ P = g_P[split];

    floatx4 acc[2][2];
#pragma unroll
    for (int a = 0; a < 2; ++a)
#pragma unroll
        for (int b = 0; b < 2; ++b) acc[a][b] = (floatx4)0.0f;

    const int rS = tid >> 2;
    const int jS = tid & 3;
    const int s0 = ((rS & 15) >> 1) & 3;
    char* asW = (char*)As + rS * 64 + ((jS ^ s0) * 16);
    char* bsW = (char*)Bs + rS * 64 + ((jS ^ s0) * 16);
    const _Float16* gA = g_Ap + (size_t)(mi0 + rS) * K_DIM + ks + jS * 8;
    const _Float16* gB = g_Bt + (size_t)(ni0 + rS) * K_DIM + ks + jS * 8;

    const int rowA = lane & 15;
    const int q    = lane >> 4;
    const int coff = (q ^ ((rowA >> 1) & 3)) * 16;

    const int NIT = 1280 / 64;           // 20

    // in-flight register sets: set[(kt+1)&1] holds slab kt+1 during iter kt
    half8 sA0[2], sA1[2], sB0[2], sB1[2];

    {   // prologue: slab 0 -> LDS buf 0 (direct); slab 1 -> set[1]
        half8 a0 = *reinterpret_cast<const half8*>(gA);
        half8 a1 = *reinterpret_cast<const half8*>(gA + 32);
        half8 b0 = *reinterpret_cast<const half8*>(gB);
        half8 b1 = *reinterpret_cast<const half8*>(gB + 32);
        sA0[1] = *reinterpret_cast<const half8*>(gA + 64);
        sA1[1] = *reinterpret_cast<const half8*>(gA + 96);
        sB0[1] = *reinterpret_cast<const half8*>(gB + 64);
        sB1[1] = *reinterpret_cast<const half8*>(gB + 96);
        *reinterpret_cast<half8*>(asW)        = a0;
        *reinterpret_cast<half8*>(asW + 4096) = a1;
        *reinterpret_cast<half8*>(bsW)        = b0;
        *reinterpret_cast<half8*>(bsW + 4096) = b1;
    }
    __syncthreads();

#pragma unroll 2
    for (int kt = 0; kt < NIT; ++kt) {
        const int cur = kt & 1;
        const int nxt = cur ^ 1;
        if (kt + 2 < NIT) {              // issue slab kt+2 into set[cur]
            const _Float16* ga = gA + (size_t)(kt + 2) * 64;
            const _Float16* gb = gB + (size_t)(kt + 2) * 64;
            sA0[cur] = *reinterpret_cast<const half8*>(ga);
            sA1[cur] = *reinterpret_cast<const half8*>(ga + 32);
            sB0[cur] = *reinterpret_cast<const half8*>(gb);
            sB1[cur] = *reinterpret_cast<const half8*>(gb + 32);
        }
        const char* Ab = (const char*)As + cur * 8192;
        const char* Bb = (const char*)Bs + cur * 8192;
        half8 af[2][2], bf[2][2];
#pragma unroll
        for (int mi = 0; mi < 2; ++mi) {
            int r = wm * 32 + mi * 16 + rowA;
            af[mi][0] = *reinterpret_cast<const half8*>(Ab + r * 64 + coff);
            af[mi][1] = *reinterpret_cast<const half8*>(Ab + 4096 + r * 64 + coff);
        }
#pragma unroll
        for (int ni = 0; ni < 2; ++ni) {
            int r = wn * 32 + ni * 16 + rowA;
            bf[ni][0] = *reinterpret_cast<const half8*>(Bb + r * 64 + coff);
            bf[ni][1] = *reinterpret_cast<const half8*>(Bb + 4096 + r * 64 + coff);
        }
#pragma unroll
        for (int mi = 0; mi < 2; ++mi)
#pragma unroll
            for (int ni = 0; ni < 2; ++ni) {
                acc[mi][ni] = __builtin_amdgcn_mfma_f32_16x16x32_f16(
                    af[mi][0], bf[ni][0], acc[mi][ni], 0, 0, 0);
                acc[mi][ni] = __builtin_amdgcn_mfma_f32_16x16x32_f16(
                    af[mi][1], bf[ni][1], acc[mi][ni], 0, 0, 0);
            }
        if (kt + 1 < NIT) {              // store slab kt+1 (loaded >=1 iter ago)
            char* aw = asW + nxt * 8192;
            char* bw = bsW + nxt * 8192;
            *reinterpret_cast<half8*>(aw)        = sA0[nxt];
            *reinterpret_cast<half8*>(aw + 4096) = sA1[nxt];
            *reinterpret_cast<half8*>(bw)        = sB0[nxt];
            *reinterpret_cast<half8*>(bw + 4096) = sB1[nxt];
        }
        __syncthreads();                 // single barrier per iter
    }

    // store f32 partial tile (C/D layout: col=lane&15, row=(lane>>4)*4+reg)
    const int colL  = lane & 15;
    const int rquad = (lane >> 4) * 4;
#pragma unroll
    for (int mi = 0; mi < 2; ++mi)
#pragma unroll
        for (int ni = 0; ni < 2; ++ni)
#pragma unroll
            for (int r = 0; r < 4; ++r) {
                int row = mi0 + wm * 32 + mi * 16 + rquad + r;
                int col = ni0 + wn * 32 + ni * 16 + colL;
                P[(size_t)row * 2048 + col] = acc[mi][ni][r];
            }
}

// ---------------- epilogue: reduce 2 splits + complex soft-threshold --------
__global__ __launch_bounds__(256) void reduce_soft(float* __restrict__ out,
                                                   int out_n)
{
    int t = blockIdx.x * 256 + threadIdx.x;          // 0..524287
    floatx4 v0 = reinterpret_cast<const floatx4*>(g_P[0])[t];
    floatx4 v1 = reinterpret_cast<const floatx4*>(g_P[1])[t];
    float re0 = v0[0] + v1[0], im0 = v0[1] + v1[1];
    float re1 = v0[2] + v1[2], im1 = v0[3] + v1[3];
    float m0 = sqrtf(re0 * re0 + im0 * im0);
    float m1 = sqrtf(re1 * re1 + im1 * im1);
    float s0 = fmaxf(m0 - BETA_F, 0.0f) / fmaxf(m0, EPS_F);
    float s1 = fmaxf(m1 - BETA_F, 0.0f) / fmaxf(m1, EPS_F);
    float2 r = make_float2(re0 * s0, re1 * s1);
    int idx = t * 2;                                  // flat Re-output index
    if (idx + 1 < out_n)
        *reinterpret_cast<float2*>(out + idx) = r;
}

// ---------------- launcher ---------------------------------------------------
extern "C" void kernel_launch(void* const* d_in, const int* in_sizes, int n_in,
                              void* d_out, int out_size, void* d_ws, size_t ws_size,
                              hipStream_t stream) {
    (void)d_ws; (void)ws_size; (void)in_sizes; (void)n_in;
    const float* v_re  = (const float*)d_in[0];
    const float* v_im  = (const float*)d_in[1];
    const float* W2_re = (const float*)d_in[2];
    const float* W2_im = (const float*)d_in[3];
    const float* x_re  = (const float*)d_in[4];
    const float* x_im  = (const float*)d_in[5];
    const float* y_re  = (const float*)d_in[6];
    const float* y_im  = (const float*)d_in[7];
    float* out = (float*)d_out;

    build_all<<<2560, 256, 0, stream>>>(v_re, v_im, W2_re, W2_im,
                                        x_re, x_im, y_re, y_im);
    gemm_split<<<1024, 256, 0, stream>>>();
    reduce_soft<<<2048, 256, 0, stream>>>(out, out_size);
}

// Round 11
// 111.095 us; speedup vs baseline: 2.8662x; 1.0374x over previous
//
#include <hip/hip_runtime.h>
#include <hip/hip_fp16.h>
#include <cstdint>
#include <cstddef>

// z = soft_thresh(Toeplitz(v) @ x + W2 @ y, beta) -- complex, N=1024, M=256, B=1024
// Real embedding: C[1024][2048] = A'[1024][2560] @ B'[2560][2048] (layouts R0-R5).
// Output = Re(z) only: [1024,1024] f32 (R4 finding).
//
// R11 (R10 budget model: split-K overhead = 32MB partial traffic + reduce
// dispatch ~15us; R6 proved non-split 64x64 gemm = 42us even un-pipelined):
//  - TWO dispatches only: build_all, gemm_fused (non-split, K=2560, 40 iters)
//  - dbuf LDS (1 barrier/iter) + 2-deep register prefetch (R10 machinery)
//  - fused epilogue: shfl re/im pair -> soft-thresh -> write Re directly
//  - no partials, no fences (R9 lesson), XOR swizzle (0 conflicts R5-R10)

#define K_DIM 2560
#define BETA_F 0.01f
#define EPS_F  1e-12f

typedef __attribute__((ext_vector_type(8))) _Float16 half8;
typedef __attribute__((ext_vector_type(4))) _Float16 half4;
typedef __attribute__((ext_vector_type(4))) float   floatx4;

__device__ alignas(16) _Float16 g_Ap[1024 * K_DIM];      // 5 MB
__device__ alignas(16) _Float16 g_Bt[2048 * K_DIM];      // 10 MB

// ---------------- prep (merged): build A' and B' -----------------------------
__global__ __launch_bounds__(256) void build_all(
    const float* __restrict__ v_re, const float* __restrict__ v_im,
    const float* __restrict__ W2_re, const float* __restrict__ W2_im,
    const float* __restrict__ x_re, const float* __restrict__ x_im,
    const float* __restrict__ y_re, const float* __restrict__ y_im)
{
    const int bx = blockIdx.x;
    if (bx < 1280) {
        // ---- A' part: one thread per 8 halves (16B store) ----
        int t = bx * 256 + threadIdx.x;
        int i  = t / 320;
        int c  = t - i * 320;
        int kp = c * 8;                        // segment-aligned
        half8 h;
        if (kp < 1024) {
#pragma unroll
            for (int j = 0; j < 8; ++j) h[j] = (_Float16)v_re[1023 + i - kp - j];
        } else if (kp < 1280) {
            const float* s = W2_re + i * 256 + (kp - 1024);
#pragma unroll
            for (int j = 0; j < 8; ++j) h[j] = (_Float16)s[j];
        } else if (kp < 2304) {
            int k2 = kp - 1280;
#pragma unroll
            for (int j = 0; j < 8; ++j) h[j] = (_Float16)v_im[1023 + i - k2 - j];
        } else {
            const float* s = W2_im + i * 256 + (kp - 2304);
#pragma unroll
            for (int j = 0; j < 8; ++j) h[j] = (_Float16)s[j];
        }
        *reinterpret_cast<half8*>(g_Ap + (size_t)i * K_DIM + kp) = h;
        return;
    }
    // ---- B' part: transposing build ----
    __shared__ float lre[32][33];
    __shared__ float lim[32][33];
    int idx = bx - 1280;                       // 0..1279
    int bk  = idx % 40;                        // 0..39 (k-block / source select)
    int by  = idx / 40;                        // 0..31 (n-block)
    const float* sre = (bk < 32) ? x_re : y_re;
    const float* sim = (bk < 32) ? x_im : y_im;
    int kb   = (bk < 32) ? bk : (bk - 32);
    int koff = (bk < 32) ? 0 : 1024;
    int k0 = kb * 32;
    int n0 = by * 32;
    int tid = threadIdx.x;
    int tx = tid & 31, ty = tid >> 5;
#pragma unroll
    for (int s = 0; s < 4; ++s) {
        int kk = ty + 8 * s;
        lre[kk][tx] = sre[(size_t)(k0 + kk) * 1024 + n0 + tx];
        lim[kk][tx] = sim[(size_t)(k0 + kk) * 1024 + n0 + tx];
    }
    __syncthreads();
    int lane_n = tid >> 3;                     // 0..31
    int kq     = (tid & 7) * 4;                // 0,4,...,28
    half4 hre, him, hmim;
#pragma unroll
    for (int j = 0; j < 4; ++j) {
        float re = lre[kq + j][lane_n];
        float im = lim[kq + j][lane_n];
        hre[j]  = (_Float16)re;
        him[j]  = (_Float16)im;
        hmim[j] = (_Float16)(-im);
    }
    int n = n0 + lane_n;
    size_t kk2 = (size_t)koff + k0 + kq;
    _Float16* r0 = g_Bt + (size_t)(2 * n)     * K_DIM;
    _Float16* r1 = g_Bt + (size_t)(2 * n + 1) * K_DIM;
    *reinterpret_cast<half4*>(r0 + kk2)        = hre;   // Br block of re-col
    *reinterpret_cast<half4*>(r0 + kk2 + 1280) = hmim;  // -Bi block of re-col
    *reinterpret_cast<half4*>(r1 + kk2)        = him;   // Bi block of im-col
    *reinterpret_cast<half4*>(r1 + kk2 + 1280) = hre;   // Br block of im-col
}

// ---------------- non-split GEMM + fused soft-threshold ----------------------
// 64x64 tile, BK=64, 512 blocks (2/CU), 4 waves = 2x2 of 32x32, K=2560.
// Dbuf LDS (1 barrier/iter), 2-deep register prefetch, XOR swizzle.
__global__ __launch_bounds__(256, 4) void gemm_fused(float* __restrict__ out,
                                                     int out_n)
{
    __shared__ __align__(16) _Float16 As[2 * 2 * 64 * 32];  // [buf][ksub][row][32h]
    __shared__ __align__(16) _Float16 Bs[2 * 2 * 64 * 32];

    const int tid  = threadIdx.x;
    const int lane = tid & 63;
    const int w    = tid >> 6;
    const int wm   = w >> 1;
    const int wn   = w & 1;

    const int bid = blockIdx.x;          // 0..511
    const int xcd = bid & 7;             // round-robin -> XCD; 8x8 super-tile
    const int t   = bid >> 3;            // 0..63
    const int mi0 = ((xcd & 1) * 8 + (t & 7)) * 64;       // 0..960
    const int ni0 = ((xcd >> 1) * 8 + (t >> 3)) * 64;     // 0..1984

    floatx4 acc[2][2];
#pragma unroll
    for (int a = 0; a < 2; ++a)
#pragma unroll
        for (int b = 0; b < 2; ++b) acc[a][b] = (floatx4)0.0f;

    const int rS = tid >> 2;
    const int jS = tid & 3;
    const int s0 = ((rS & 15) >> 1) & 3;
    char* asW = (char*)As + rS * 64 + ((jS ^ s0) * 16);
    char* bsW = (char*)Bs + rS * 64 + ((jS ^ s0) * 16);
    const _Float16* gA = g_Ap + (size_t)(mi0 + rS) * K_DIM + jS * 8;
    const _Float16* gB = g_Bt + (size_t)(ni0 + rS) * K_DIM + jS * 8;

    const int rowA = lane & 15;
    const int q    = lane >> 4;
    const int coff = (q ^ ((rowA >> 1) & 3)) * 16;

    const int NIT = K_DIM / 64;          // 40

    // in-flight register sets: set[(kt+1)&1] holds slab kt+1 during iter kt
    half8 sA0[2], sA1[2], sB0[2], sB1[2];

    {   // prologue: slab 0 -> LDS buf 0 (direct); slab 1 -> set[1]
        half8 a0 = *reinterpret_cast<const half8*>(gA);
        half8 a1 = *reinterpret_cast<const half8*>(gA + 32);
        half8 b0 = *reinterpret_cast<const half8*>(gB);
        half8 b1 = *reinterpret_cast<const half8*>(gB + 32);
        sA0[1] = *reinterpret_cast<const half8*>(gA + 64);
        sA1[1] = *reinterpret_cast<const half8*>(gA + 96);
        sB0[1] = *reinterpret_cast<const half8*>(gB + 64);
        sB1[1] = *reinterpret_cast<const half8*>(gB + 96);
        *reinterpret_cast<half8*>(asW)        = a0;
        *reinterpret_cast<half8*>(asW + 4096) = a1;
        *reinterpret_cast<half8*>(bsW)        = b0;
        *reinterpret_cast<half8*>(bsW + 4096) = b1;
    }
    __syncthreads();

#pragma unroll 2
    for (int kt = 0; kt < NIT; ++kt) {
        const int cur = kt & 1;
        const int nxt = cur ^ 1;
        if (kt + 2 < NIT) {              // issue slab kt+2 into set[cur]
            const _Float16* ga = gA + (size_t)(kt + 2) * 64;
            const _Float16* gb = gB + (size_t)(kt + 2) * 64;
            sA0[cur] = *reinterpret_cast<const half8*>(ga);
            sA1[cur] = *reinterpret_cast<const half8*>(ga + 32);
            sB0[cur] = *reinterpret_cast<const half8*>(gb);
            sB1[cur] = *reinterpret_cast<const half8*>(gb + 32);
        }
        const char* Ab = (const char*)As + cur * 8192;
        const char* Bb = (const char*)Bs + cur * 8192;
        half8 af[2][2], bf[2][2];
#pragma unroll
        for (int mi = 0; mi < 2; ++mi) {
            int r = wm * 32 + mi * 16 + rowA;
            af[mi][0] = *reinterpret_cast<const half8*>(Ab + r * 64 + coff);
            af[mi][1] = *reinterpret_cast<const half8*>(Ab + 4096 + r * 64 + coff);
        }
#pragma unroll
        for (int ni = 0; ni < 2; ++ni) {
            int r = wn * 32 + ni * 16 + rowA;
            bf[ni][0] = *reinterpret_cast<const half8*>(Bb + r * 64 + coff);
            bf[ni][1] = *reinterpret_cast<const half8*>(Bb + 4096 + r * 64 + coff);
        }
#pragma unroll
        for (int mi = 0; mi < 2; ++mi)
#pragma unroll
            for (int ni = 0; ni < 2; ++ni) {
                acc[mi][ni] = __builtin_amdgcn_mfma_f32_16x16x32_f16(
                    af[mi][0], bf[ni][0], acc[mi][ni], 0, 0, 0);
                acc[mi][ni] = __builtin_amdgcn_mfma_f32_16x16x32_f16(
                    af[mi][1], bf[ni][1], acc[mi][ni], 0, 0, 0);
            }
        if (kt + 1 < NIT) {              // store slab kt+1 (loaded >=1 iter ago)
            char* aw = asW + nxt * 8192;
            char* bw = bsW + nxt * 8192;
            *reinterpret_cast<half8*>(aw)        = sA0[nxt];
            *reinterpret_cast<half8*>(aw + 4096) = sA1[nxt];
            *reinterpret_cast<half8*>(bw)        = sB0[nxt];
            *reinterpret_cast<half8*>(bw + 4096) = sB1[nxt];
        }
        __syncthreads();                 // single barrier per iter
    }

    // epilogue: C/D col=lane&15, row=(lane>>4)*4+reg; lane^1 = re/im partner.
    // Output = Re(z) only: even C'-columns -> out[row*1024 + col/2].
    const int colL  = lane & 15;
    const int rquad = (lane >> 4) * 4;
#pragma unroll
    for (int mi = 0; mi < 2; ++mi)
#pragma unroll
        for (int ni = 0; ni < 2; ++ni)
#pragma unroll
            for (int r = 0; r < 4; ++r) {
                float c = acc[mi][ni][r];
                float p = __shfl_xor(c, 1, 64);
                float mag = sqrtf(c * c + p * p);
                float s = fmaxf(mag - BETA_F, 0.0f) / fmaxf(mag, EPS_F);
                int row = mi0 + wm * 32 + mi * 16 + rquad + r;
                int col = ni0 + wn * 32 + ni * 16 + colL;   // C' col (0..2047)
                if ((col & 1) == 0) {                        // even = Re lane
                    size_t idx = (size_t)row * 1024 + (col >> 1);
                    if (idx < (size_t)out_n) out[idx] = c * s;
                }
            }
}

// ---------------- launcher ---------------------------------------------------
extern "C" void kernel_launch(void* const* d_in, const int* in_sizes, int n_in,
                              void* d_out, int out_size, void* d_ws, size_t ws_size,
                              hipStream_t stream) {
    (void)d_ws; (void)ws_size; (void)in_sizes; (void)n_in;
    const float* v_re  = (const float*)d_in[0];
    const float* v_im  = (const float*)d_in[1];
    const float* W2_re = (const float*)d_in[2];
    const float* W2_im = (const float*)d_in[3];
    const float* x_re  = (const float*)d_in[4];
    const float* x_im  = (const float*)d_in[5];
    const float* y_re  = (const float*)d_in[6];
    const float* y_im  = (const float*)d_in[7];
    float* out = (float*)d_out;

    build_all<<<2560, 256, 0, stream>>>(v_re, v_im, W2_re, W2_im,
                                        x_re, x_im, y_re, y_im);
    gemm_fused<<<512, 256, 0, stream>>>(out, out_size);
}